// Round 8
// baseline (714.778 us; speedup 1.0000x reference)
//
#include <hip/hip_runtime.h>
#include <hip/hip_bf16.h>
#include <math.h>

#define B_ 64
#define N_ 100
#define C_ 92

// ---- bbox helpers (f32, fp-contract OFF to mirror strict numpy per-op IEEE) ----

__device__ __forceinline__ void cxcywh_to_xyxy(const float q[4], float o[4]) {
#pragma clang fp contract(off)
  float cx = q[0], cy = q[1], w = q[2], h = q[3];
  o[0] = cx - w * 0.5f;
  o[1] = cy - h * 0.5f;
  o[2] = cx + w * 0.5f;
  o[3] = cy + h * 0.5f;
}

__device__ __forceinline__ float pair_bbox_loss(const float* p, const float* t) {
#pragma clang fp contract(off)
  const float EPS = 1e-7f;
  float px1 = p[0], py1 = p[1], px2 = p[2], py2 = p[3];
  float tx1 = t[0], ty1 = t[1], tx2 = t[2], ty2 = t[3];
  float iw = fminf(px2, tx2) - fmaxf(px1, tx1); iw = fmaxf(iw, 0.0f);
  float ih = fminf(py2, ty2) - fmaxf(py1, ty1); ih = fmaxf(ih, 0.0f);
  float inter = iw * ih;
  float uni = (px2 - px1) * (py2 - py1) + (tx2 - tx1) * (ty2 - ty1) - inter;
  float iou = inter / (uni + EPS);
  float cw = fmaxf(px2, tx2) - fminf(px1, tx1);
  float ch = fmaxf(py2, ty2) - fminf(py1, ty1);
  float diag2 = cw * cw + ch * ch + EPS;
  float dx = (px1 + px2) * 0.5f - (tx1 + tx2) * 0.5f;
  float dy = (py1 + py2) * 0.5f - (ty1 + ty2) * 0.5f;
  float diou = 1.0f - iou + (dx * dx + dy * dy) / diag2;
  float s = 0.0f;
  for (int k = 0; k < 4; ++k) {
    float d = p[k] - t[k];
    float ad = fabsf(d);
    s += (ad < 1.0f) ? 0.5f * d * d : ad - 0.5f;
  }
  return diou + s * 0.25f;
}

__device__ __forceinline__ int rdlane(int v, int srcLane) {
  return __builtin_amdgcn_readlane(v, srcLane);
}

// DPP min step on f64: x = fmin(x, dpp_shuffled(x)); invalid lanes keep old
// (update_dpp old=own value, bound_ctrl=false) -> identity for min. Exact.
template <int CTRL>
__device__ __forceinline__ double dminstep(double x) {
  int lo = __double2loint(x), hi = __double2hiint(x);
  int slo = __builtin_amdgcn_update_dpp(lo, lo, CTRL, 0xF, 0xF, false);
  int shi = __builtin_amdgcn_update_dpp(hi, hi, CTRL, 0xF, 0xF, false);
  return fmin(x, __hiloint2double(shi, slo));
}

// DPP min step on u32 keys (identity-preserving for invalid lanes).
template <int CTRL>
__device__ __forceinline__ unsigned uminstep(unsigned x) {
  int s = __builtin_amdgcn_update_dpp((int)x, (int)x, CTRL, 0xF, 0xF, false);
  unsigned su = (unsigned)s;
  return x < su ? x : su;
}

// read u[i0] from register-distributed rows
__device__ __forceinline__ double read_u(double uA, double uB, int i0) {
  bool inA = (i0 <= 64);                 // i0 is wave-uniform
  double src = inA ? uA : uB;
  int idx = inA ? (i0 - 1) : (i0 - 65);
  int lo = rdlane(__double2loint(src), idx);
  int hi = rdlane(__double2hiint(src), idx);
  return __hiloint2double(hi, lo);
}

// ---- Hungarian: one wave per batch. SAP state in registers (2 cols +    ----
// ---- 2 rows per lane). Argmin: u32 monotone-key DPP reduce (fast path,  ----
// ---- provably exact when key-min is unique) with exact f64-chain        ----
// ---- fallback on key ties. np.argmin first-index tie-break preserved.   ----
// ---- Arithmetic trajectory bit-identical to the numpy e-maxx loop.      ----

__global__ __launch_bounds__(64) void hungarian_k(
    const int* __restrict__ targ_cat, const float* __restrict__ targ_bbox,
    const float* __restrict__ pred_cat, const float* __restrict__ pred_bbox,
    int* __restrict__ assign_ws, float* __restrict__ assign_out) {
  const int b = blockIdx.x;
  const int lane = threadIdx.x;

  __shared__ float costL[N_ * N_ + 64];  // +64 pad: unconditional base[64] reads
  __shared__ float tb[N_ * 4];
  __shared__ float pbx[N_ * 4];
  __shared__ int tcat[N_];

  // stage boxes (xyxy) + categories
  for (int i = lane; i < N_; i += 64) {
    float q[4], o[4];
    q[0] = targ_bbox[(b * N_ + i) * 4 + 0];
    q[1] = targ_bbox[(b * N_ + i) * 4 + 1];
    q[2] = targ_bbox[(b * N_ + i) * 4 + 2];
    q[3] = targ_bbox[(b * N_ + i) * 4 + 3];
    cxcywh_to_xyxy(q, o);
    tb[i * 4 + 0] = o[0]; tb[i * 4 + 1] = o[1]; tb[i * 4 + 2] = o[2]; tb[i * 4 + 3] = o[3];
    q[0] = pred_bbox[(b * N_ + i) * 4 + 0];
    q[1] = pred_bbox[(b * N_ + i) * 4 + 1];
    q[2] = pred_bbox[(b * N_ + i) * 4 + 2];
    q[3] = pred_bbox[(b * N_ + i) * 4 + 3];
    cxcywh_to_xyxy(q, o);
    pbx[i * 4 + 0] = o[0]; pbx[i * 4 + 1] = o[1]; pbx[i * 4 + 2] = o[2]; pbx[i * 4 + 3] = o[3];
    tcat[i] = targ_cat[b * N_ + i];
  }
  costL[N_ * N_ + lane] = 0.0f;          // zero the pad
  __syncthreads();

  // cost[n][m] = -pred_cat[b,m,tc(n)] + (tc(n)==0) * pair_bbox_loss(pred m, targ n)
  for (int e = lane; e < N_ * N_; e += 64) {
    int n = e / N_;
    int m = e - n * N_;
    int tc = tcat[n];
    float cc = -pred_cat[(b * N_ + m) * C_ + tc];
    float pl = pair_bbox_loss(&pbx[m * 4], &tb[n * 4]);
    costL[e] = cc + ((tc == 0) ? pl : 0.0f);
  }
  __syncthreads();

  const double INF = __builtin_huge_val();
  const unsigned INF_KEY = 0xFFF00000u;  // key of +inf (hi=0x7FF00000 ^ 0x80000000)
  const int jA = lane + 1;               // cols 1..64
  const int jB = lane + 65;              // cols 65..100 (lanes 0..35)
  const bool hasB = (jB <= N_);

  double vA = 0.0, vB = 0.0;             // column potentials
  double uA = 0.0, uB = 0.0;             // row potentials: u[lane+1], u[lane+65]
  int pA = 0, pB = 0;                    // matched row per column

  for (int i = 1; i <= N_; ++i) {
    double minvA = INF, minvB = INF;
    int wayA = 0, wayB = 0;
    bool usedA = false, usedB = false;
    bool fA = false, fB = false;         // row-visited flags (u receives deltas)
    int j0 = 0;
    int i0 = i;
    const float* base0 = &costL[(i0 - 1) * N_ + lane];
    float cA = base0[0];
    float cB = base0[64];                // pad makes this safe; unused if !hasB
    double ui0 = read_u(uA, uB, i0);
    int it = 0;
    bool ok = true;

    while (true) {
      // mark used column j0 (first iter: j0==0, none); flag visited row i0
      if (j0 == jA) usedA = true;
      if (j0 == jB) usedB = true;
      fA = fA || (i0 == jA);
      fB = fB || (i0 == jB);

      if (!usedA) {
        double cur = (double)cA - ui0 - vA;
        if (cur < minvA) { minvA = cur; wayA = j0; }
      }
      if (hasB && !usedB) {
        double cur = (double)cB - ui0 - vB;
        if (cur < minvB) { minvB = cur; wayB = j0; }
      }

      double cvA = usedA ? INF : minvA;
      double cvB = (hasB && !usedB) ? minvB : INF;
      double cv = fmin(cvA, cvB);        // per-lane min (A preferred on tie below)

      // monotone u32 key of cv's high word: strict key-min => strict f64 min
      int hi = __double2hiint(cv);
      unsigned key = (unsigned)hi ^ ((hi < 0) ? 0xFFFFFFFFu : 0x80000000u);
      unsigned kr = key;
      kr = uminstep<0x111>(kr);          // row_shr:1
      kr = uminstep<0x112>(kr);          // row_shr:2
      kr = uminstep<0x114>(kr);          // row_shr:4
      kr = uminstep<0x118>(kr);          // row_shr:8
      kr = uminstep<0x142>(kr);          // row_bcast15
      kr = uminstep<0x143>(kr);          // row_bcast31 -> lane 63 = min key
      unsigned kmin = (unsigned)rdlane((int)kr, 63);
      if (kmin == INF_KEY) { ok = false; break; }   // all INF: unreachable

      unsigned long long tied = __ballot(key == kmin);
      unsigned long long aWins = __ballot(cvA <= cvB);   // lane-min came from A
      int j1;
      double delta;
      if (__popcll(tied) == 1) {
        // unique strict minimum lane: exact argmin, first-index trivially holds
        int l = __builtin_ctzll(tied);
        j1 = ((aWins >> l) & 1ull) ? (l + 1) : (l + 65);
        // issue next-row loads ASAP (delta not needed for the address)
        int pj1x = (j1 <= 64) ? rdlane(pA, j1 - 1) : rdlane(pB, j1 - 65);
        int ni0 = (pj1x == 0) ? 1 : pj1x;
        const float* nb = &costL[(ni0 - 1) * N_ + lane];
        float nA = nb[0];
        float nB = nb[64];
        double nui0 = read_u(uA, uB, ni0);
        delta = __hiloint2double(rdlane(__double2hiint(cv), l),
                                 rdlane(__double2loint(cv), l));
        // updates
        if (fA) uA += delta;
        if (fB) uB += delta;
        if (usedA) { vA -= delta; } else { minvA -= delta; }
        if (hasB) { if (usedB) { vB -= delta; } else { minvB -= delta; } }
        j0 = j1;
        if (pj1x == 0) break;
        i0 = ni0; ui0 = nui0; cA = nA; cB = nB;
      } else {
        // exact fallback (key ties): f64 DPP chain + two-range first-index argmin
        double rm = cv;
        rm = dminstep<0x111>(rm);
        rm = dminstep<0x112>(rm);
        rm = dminstep<0x114>(rm);
        rm = dminstep<0x118>(rm);
        rm = dminstep<0x142>(rm);
        rm = dminstep<0x143>(rm);
        delta = __hiloint2double(rdlane(__double2hiint(rm), 63),
                                 rdlane(__double2loint(rm), 63));
        unsigned long long mA = __ballot(cvA == delta);
        unsigned long long mB = __ballot(cvB == delta);
        j1 = mA ? (__builtin_ctzll(mA) + 1)
                : (mB ? (__builtin_ctzll(mB) + 65) : 0);
        if (j1 == 0) { ok = false; break; }
        int pj1x = (j1 <= 64) ? rdlane(pA, j1 - 1) : rdlane(pB, j1 - 65);
        int ni0 = (pj1x == 0) ? 1 : pj1x;
        const float* nb = &costL[(ni0 - 1) * N_ + lane];
        float nA = nb[0];
        float nB = nb[64];
        double nui0 = read_u(uA, uB, ni0);
        if (fA) uA += delta;
        if (fB) uB += delta;
        if (usedA) { vA -= delta; } else { minvA -= delta; }
        if (hasB) { if (usedB) { vB -= delta; } else { minvB -= delta; } }
        j0 = j1;
        if (pj1x == 0) break;
        i0 = ni0; ui0 = nui0; cA = nA; cB = nB;
      }
      if (++it > 2 * N_ + 8) { ok = false; break; }
    }

    // augmenting-path reconstruction: uniform scalar walk over register state
    if (ok) {
      int jj = j0;
      int hop = 0;
      while (jj != 0 && ++hop <= N_ + 2) {
        int jp = (jj <= 64) ? rdlane(wayA, jj - 1) : rdlane(wayB, jj - 65);
        int pv = (jp == 0) ? i
                           : ((jp <= 64) ? rdlane(pA, jp - 1) : rdlane(pB, jp - 65));
        if (jj <= 64) { if (lane == jj - 1) pA = pv; }
        else          { if (lane == jj - 65) pB = pv; }
        jj = jp;
      }
    }
  }

  // ans[p[j]-1] = j-1  (float32 outputs)
  {
    int row = pA - 1;
    if (row < 0) row = 0;
    if (row >= N_) row = N_ - 1;
    assign_ws[b * N_ + row] = jA - 1;
    assign_out[b * N_ + row] = (float)(jA - 1);
    if (hasB) {
      int r2 = pB - 1;
      if (r2 < 0) r2 = 0;
      if (r2 >= N_) r2 = N_ - 1;
      assign_ws[b * N_ + r2] = jB - 1;
      assign_out[b * N_ + r2] = (float)(jB - 1);
    }
  }
}

// ---- per-row losses: CE (log_softmax gather) + matched bbox pair loss ----

__global__ __launch_bounds__(256) void loss_rows_k(
    const int* __restrict__ targ_cat, const float* __restrict__ targ_bbox,
    const float* __restrict__ pred_cat, const float* __restrict__ pred_bbox,
    const int* __restrict__ assign,
    float* __restrict__ ce, float* __restrict__ lb, int* __restrict__ msk) {
  int t = blockIdx.x * blockDim.x + threadIdx.x;
  if (t >= B_ * N_) return;
  int b = t / N_;
  int m = assign[t];
  if (m < 0) m = 0;
  if (m >= N_) m = N_ - 1;
  int tc = targ_cat[t];

  const float* row = &pred_cat[(b * N_ + m) * C_];
  float vals[C_];
  const float4* row4 = (const float4*)row;   // 368B row stride = 16B-aligned
#pragma unroll
  for (int k = 0; k < C_ / 4; ++k) {
    float4 w = row4[k];
    vals[4 * k + 0] = w.x; vals[4 * k + 1] = w.y;
    vals[4 * k + 2] = w.z; vals[4 * k + 3] = w.w;
  }
  float mx = -INFINITY;
#pragma unroll
  for (int c = 0; c < C_; ++c) mx = fmaxf(mx, vals[c]);
  float se = 0.0f;
#pragma unroll
  for (int c = 0; c < C_; ++c) se += expf(vals[c] - mx);
  ce[t] = mx + logf(se) - vals[tc];

  float q[4], po[4], to_[4];
  q[0] = pred_bbox[(b * N_ + m) * 4 + 0];
  q[1] = pred_bbox[(b * N_ + m) * 4 + 1];
  q[2] = pred_bbox[(b * N_ + m) * 4 + 2];
  q[3] = pred_bbox[(b * N_ + m) * 4 + 3];
  cxcywh_to_xyxy(q, po);
  q[0] = targ_bbox[t * 4 + 0];
  q[1] = targ_bbox[t * 4 + 1];
  q[2] = targ_bbox[t * 4 + 2];
  q[3] = targ_bbox[t * 4 + 3];
  cxcywh_to_xyxy(q, to_);
  float l = pair_bbox_loss(po, to_);
  bool mk = (tc != 0);
  lb[t] = mk ? l : 0.0f;
  msk[t] = mk ? 1 : 0;
}

// ---- deterministic final reduction -> float32 loss scalar ----

__global__ __launch_bounds__(256) void finalize_k(
    const float* __restrict__ ce, const float* __restrict__ lb,
    const int* __restrict__ msk, float* __restrict__ out) {
  __shared__ double s1[256];
  __shared__ double s2[256];
  __shared__ int s3[256];
  int tid = threadIdx.x;
  double a = 0.0, c2 = 0.0;
  int c3 = 0;
  for (int t = tid; t < B_ * N_; t += 256) {
    a += (double)ce[t]; c2 += (double)lb[t]; c3 += msk[t];
  }
  s1[tid] = a; s2[tid] = c2; s3[tid] = c3;
  __syncthreads();
  for (int off = 128; off > 0; off >>= 1) {
    if (tid < off) {
      s1[tid] += s1[tid + off]; s2[tid] += s2[tid + off]; s3[tid] += s3[tid + off];
    }
    __syncthreads();
  }
  if (tid == 0) {
    double loss = s1[0] / (double)(B_ * N_) + s2[0] / (double)s3[0];
    out[0] = (float)loss;
  }
}

extern "C" void kernel_launch(void* const* d_in, const int* in_sizes, int n_in,
                              void* d_out, int out_size, void* d_ws, size_t ws_size,
                              hipStream_t stream) {
  const int* targ_cat = (const int*)d_in[0];
  const float* targ_bbox = (const float*)d_in[1];
  const float* pred_cat = (const float*)d_in[2];
  const float* pred_bbox = (const float*)d_in[3];
  float* out = (float*)d_out;   // [0] = loss, [1..6400] = assign (as float32)

  char* ws = (char*)d_ws;
  int* assign_ws = (int*)(ws);             // 25.6 KB
  float* ce = (float*)(ws + (32 << 10));   // 25.6 KB
  float* lb = (float*)(ws + (64 << 10));   // 25.6 KB
  int* msk = (int*)(ws + (96 << 10));      // 25.6 KB  (total 128 KB)

  hipLaunchKernelGGL(hungarian_k, dim3(B_), dim3(64), 0, stream,
                     targ_cat, targ_bbox, pred_cat, pred_bbox, assign_ws, out + 1);
  hipLaunchKernelGGL(loss_rows_k, dim3((B_ * N_ + 255) / 256), dim3(256), 0, stream,
                     targ_cat, targ_bbox, pred_cat, pred_bbox, assign_ws, ce, lb, msk);
  hipLaunchKernelGGL(finalize_k, dim3(1), dim3(256), 0, stream, ce, lb, msk, out);
}

// Round 9
// 649.128 us; speedup vs baseline: 1.1011x; 1.1011x over previous
//
#include <hip/hip_runtime.h>
#include <hip/hip_bf16.h>
#include <math.h>

#define B_ 64
#define N_ 100
#define C_ 92

typedef float f32x32 __attribute__((ext_vector_type(32)));
typedef float f32x4  __attribute__((ext_vector_type(4)));

// ---- bbox helpers (f32, fp-contract OFF to mirror strict numpy per-op IEEE) ----

__device__ __forceinline__ void cxcywh_to_xyxy(const float q[4], float o[4]) {
#pragma clang fp contract(off)
  float cx = q[0], cy = q[1], w = q[2], h = q[3];
  o[0] = cx - w * 0.5f;
  o[1] = cy - h * 0.5f;
  o[2] = cx + w * 0.5f;
  o[3] = cy + h * 0.5f;
}

__device__ __forceinline__ float pair_bbox_loss(const float* p, const float* t) {
#pragma clang fp contract(off)
  const float EPS = 1e-7f;
  float px1 = p[0], py1 = p[1], px2 = p[2], py2 = p[3];
  float tx1 = t[0], ty1 = t[1], tx2 = t[2], ty2 = t[3];
  float iw = fminf(px2, tx2) - fmaxf(px1, tx1); iw = fmaxf(iw, 0.0f);
  float ih = fminf(py2, ty2) - fmaxf(py1, ty1); ih = fmaxf(ih, 0.0f);
  float inter = iw * ih;
  float uni = (px2 - px1) * (py2 - py1) + (tx2 - tx1) * (ty2 - ty1) - inter;
  float iou = inter / (uni + EPS);
  float cw = fmaxf(px2, tx2) - fminf(px1, tx1);
  float ch = fmaxf(py2, ty2) - fminf(py1, ty1);
  float diag2 = cw * cw + ch * ch + EPS;
  float dx = (px1 + px2) * 0.5f - (tx1 + tx2) * 0.5f;
  float dy = (py1 + py2) * 0.5f - (ty1 + ty2) * 0.5f;
  float diou = 1.0f - iou + (dx * dx + dy * dy) / diag2;
  float s = 0.0f;
  for (int k = 0; k < 4; ++k) {
    float d = p[k] - t[k];
    float ad = fabsf(d);
    s += (ad < 1.0f) ? 0.5f * d * d : ad - 0.5f;
  }
  return diou + s * 0.25f;
}

__device__ __forceinline__ int rdlane(int v, int srcLane) {
  return __builtin_amdgcn_readlane(v, srcLane);
}

// DPP min step on f64: x = fmin(x, dpp_shuffled(x)); invalid lanes keep old
// (update_dpp old=own value, bound_ctrl=false) -> identity for min. Exact.
template <int CTRL>
__device__ __forceinline__ double dminstep(double x) {
  int lo = __double2loint(x), hi = __double2hiint(x);
  int slo = __builtin_amdgcn_update_dpp(lo, lo, CTRL, 0xF, 0xF, false);
  int shi = __builtin_amdgcn_update_dpp(hi, hi, CTRL, 0xF, 0xF, false);
  return fmin(x, __hiloint2double(shi, slo));
}

// read u[i0] from register-distributed rows
__device__ __forceinline__ double read_u(double uA, double uB, int i0) {
  bool inA = (i0 <= 64);                 // i0 is wave-uniform
  double src = inA ? uA : uB;
  int idx = inA ? (i0 - 1) : (i0 - 65);
  int lo = rdlane(__double2loint(src), idx);
  int hi = rdlane(__double2hiint(src), idx);
  return __hiloint2double(hi, lo);
}

// extract element r (wave-uniform, 0..99) from a lane's 100-row column held in
// registers as 3x f32x32 + f32x4. Lowers to GPR-index (m0) reads, not LDS.
__device__ __forceinline__ float vext100(const f32x32& a0, const f32x32& a1,
                                         const f32x32& a2, const f32x4& a3, int r) {
  int off = r & 31;
  int q = r >> 5;
  float e0 = a0[off];
  float e1 = a1[off];
  float e2 = a2[off];
  float e3 = a3[off & 3];
  float x01 = (q & 1) ? e1 : e0;
  float x23 = (q & 1) ? e3 : e2;
  return (q & 2) ? x23 : x01;
}

// ---- Hungarian: one wave per batch. Cost columns pinned in VGPRs (asm   ----
// ---- barrier prevents LDS forwarding); SAP state in registers; DPP f64  ----
// ---- min-reduce; ballot argmin (np.argmin first-index tie-break).       ----
// ---- Arithmetic trajectory bit-identical to the numpy e-maxx loop.      ----

__global__ __launch_bounds__(64, 1) void hungarian_k(
    const int* __restrict__ targ_cat, const float* __restrict__ targ_bbox,
    const float* __restrict__ pred_cat, const float* __restrict__ pred_bbox,
    int* __restrict__ assign_ws, float* __restrict__ assign_out) {
  const int b = blockIdx.x;
  const int lane = threadIdx.x;

  __shared__ float costL[N_ * N_];   // [target_row][pred_col] (build staging)
  __shared__ float tb[N_ * 4];
  __shared__ float pbx[N_ * 4];
  __shared__ int tcat[N_];

  // stage boxes (xyxy) + categories
  for (int i = lane; i < N_; i += 64) {
    float q[4], o[4];
    q[0] = targ_bbox[(b * N_ + i) * 4 + 0];
    q[1] = targ_bbox[(b * N_ + i) * 4 + 1];
    q[2] = targ_bbox[(b * N_ + i) * 4 + 2];
    q[3] = targ_bbox[(b * N_ + i) * 4 + 3];
    cxcywh_to_xyxy(q, o);
    tb[i * 4 + 0] = o[0]; tb[i * 4 + 1] = o[1]; tb[i * 4 + 2] = o[2]; tb[i * 4 + 3] = o[3];
    q[0] = pred_bbox[(b * N_ + i) * 4 + 0];
    q[1] = pred_bbox[(b * N_ + i) * 4 + 1];
    q[2] = pred_bbox[(b * N_ + i) * 4 + 2];
    q[3] = pred_bbox[(b * N_ + i) * 4 + 3];
    cxcywh_to_xyxy(q, o);
    pbx[i * 4 + 0] = o[0]; pbx[i * 4 + 1] = o[1]; pbx[i * 4 + 2] = o[2]; pbx[i * 4 + 3] = o[3];
    tcat[i] = targ_cat[b * N_ + i];
  }
  __syncthreads();

  // cost[n][m] = -pred_cat[b,m,tc(n)] + (tc(n)==0) * pair_bbox_loss(pred m, targ n)
  for (int e = lane; e < N_ * N_; e += 64) {
    int n = e / N_;
    int m = e - n * N_;
    int tc = tcat[n];
    float cc = -pred_cat[(b * N_ + m) * C_ + tc];
    float pl = pair_bbox_loss(&pbx[m * 4], &tb[n * 4]);
    costL[e] = cc + ((tc == 0) ? pl : 0.0f);
  }
  __syncthreads();

  const double INF = __builtin_huge_val();
  const int jA = lane + 1;              // cols 1..64
  const int jB = lane + 65;             // cols 65..100 (lanes 0..35)
  const bool hasB = (jB <= N_);

  // my column(s) into registers: aX[k] = cost[row][myCol]
  f32x32 a0, a1, a2; f32x4 a3;
  f32x32 b0 = {}, b1 = {}, b2 = {}; f32x4 b3 = {};
#pragma unroll
  for (int k = 0; k < 32; ++k) {
    a0[k] = costL[k * N_ + lane];
    a1[k] = costL[(32 + k) * N_ + lane];
    a2[k] = costL[(64 + k) * N_ + lane];
  }
#pragma unroll
  for (int k = 0; k < 4; ++k) a3[k] = costL[(96 + k) * N_ + lane];
  if (hasB) {
#pragma unroll
    for (int k = 0; k < 32; ++k) {
      b0[k] = costL[k * N_ + lane + 64];
      b1[k] = costL[(32 + k) * N_ + lane + 64];
      b2[k] = costL[(64 + k) * N_ + lane + 64];
    }
#pragma unroll
    for (int k = 0; k < 4; ++k) b3[k] = costL[(96 + k) * N_ + lane + 64];
  }
  // PIN: asm may-write barrier -> compiler cannot forward extracts back to LDS
  asm volatile("" : "+v"(a0), "+v"(a1), "+v"(a2), "+v"(a3),
                    "+v"(b0), "+v"(b1), "+v"(b2), "+v"(b3));

  double vA = 0.0, vB = 0.0;            // column potentials
  double uA = 0.0, uB = 0.0;            // row potentials: u[lane+1], u[lane+65]
  int pA = 0, pB = 0;                   // matched row per column

  for (int i = 1; i <= N_; ++i) {
    double minvA = INF, minvB = INF;
    int wayA = 0, wayB = 0;
    bool usedA = false, usedB = false;
    bool fA = false, fB = false;        // row-visited flags (u receives deltas)
    int j0 = 0;
    int i0 = i;
    int it = 0;
    bool ok = true;

    while (true) {
      // mark used column j0 (first iter: j0==0, none); flag visited row i0
      if (j0 == jA) usedA = true;
      if (j0 == jB) usedB = true;
      fA = fA || (i0 == jA);
      fB = fB || (i0 == jB);

      // cost[i0-1][myCol] from registers (uniform row index via m0-indexing)
      int r = __builtin_amdgcn_readfirstlane(i0) - 1;
      float cA = vext100(a0, a1, a2, a3, r);
      float cB = vext100(b0, b1, b2, b3, r);
      // u[i0]: row i0 not yet updated this phase (proven invariant)
      double ui0 = read_u(uA, uB, i0);

      if (!usedA) {
        double cur = (double)cA - ui0 - vA;
        if (cur < minvA) { minvA = cur; wayA = j0; }
      }
      if (hasB && !usedB) {
        double cur = (double)cB - ui0 - vB;
        if (cur < minvB) { minvB = cur; wayB = j0; }
      }

      // exact f64 min over unused columns: DPP reduce -> lane 63 -> broadcast
      double cvA = usedA ? INF : minvA;
      double cvB = (hasB && !usedB) ? minvB : INF;
      double rm = fmin(cvA, cvB);
      rm = dminstep<0x111>(rm);         // row_shr:1
      rm = dminstep<0x112>(rm);         // row_shr:2
      rm = dminstep<0x114>(rm);         // row_shr:4
      rm = dminstep<0x118>(rm);         // row_shr:8
      rm = dminstep<0x142>(rm);         // row_bcast15
      rm = dminstep<0x143>(rm);         // row_bcast31 -> lane 63 = global min
      double delta = __hiloint2double(rdlane(__double2hiint(rm), 63),
                                      rdlane(__double2loint(rm), 63));
      if (delta == INF) { ok = false; break; }   // unreachable for valid input

      // first-index argmin: A-range (cols 1..64) wins over B-range (65..100)
      unsigned long long mA = __ballot(cvA == delta);
      unsigned long long mB = __ballot(cvB == delta);
      int j1 = mA ? (__builtin_ctzll(mA) + 1)
                  : (mB ? (__builtin_ctzll(mB) + 65) : 0);
      if (j1 == 0) { ok = false; break; }

      int pj1 = (j1 <= 64) ? rdlane(pA, j1 - 1) : rdlane(pB, j1 - 65);

      // updates: visited rows u += delta; used cols v -= delta; else minv -= delta
      if (fA) uA += delta;
      if (fB) uB += delta;
      if (usedA) { vA -= delta; } else { minvA -= delta; }
      if (hasB) {
        if (usedB) { vB -= delta; } else { minvB -= delta; }
      }

      j0 = j1;
      if (pj1 == 0) break;              // reached an unmatched column
      i0 = pj1;
      if (++it > 2 * N_ + 8) { ok = false; break; }
    }

    // augmenting-path reconstruction: uniform scalar walk over register state
    if (ok) {
      int jj = j0;
      int hop = 0;
      while (jj != 0 && ++hop <= N_ + 2) {
        int jp = (jj <= 64) ? rdlane(wayA, jj - 1) : rdlane(wayB, jj - 65);
        int pv = (jp == 0) ? i
                           : ((jp <= 64) ? rdlane(pA, jp - 1) : rdlane(pB, jp - 65));
        if (jj <= 64) { if (lane == jj - 1) pA = pv; }
        else          { if (lane == jj - 65) pB = pv; }
        jj = jp;
      }
    }
  }

  // ans[p[j]-1] = j-1  (float32 outputs)
  {
    int row = pA - 1;
    if (row < 0) row = 0;
    if (row >= N_) row = N_ - 1;
    assign_ws[b * N_ + row] = jA - 1;
    assign_out[b * N_ + row] = (float)(jA - 1);
    if (hasB) {
      int r2 = pB - 1;
      if (r2 < 0) r2 = 0;
      if (r2 >= N_) r2 = N_ - 1;
      assign_ws[b * N_ + r2] = jB - 1;
      assign_out[b * N_ + r2] = (float)(jB - 1);
    }
  }
}

// ---- per-row losses: CE (log_softmax gather) + matched bbox pair loss ----

__global__ __launch_bounds__(256) void loss_rows_k(
    const int* __restrict__ targ_cat, const float* __restrict__ targ_bbox,
    const float* __restrict__ pred_cat, const float* __restrict__ pred_bbox,
    const int* __restrict__ assign,
    float* __restrict__ ce, float* __restrict__ lb, int* __restrict__ msk) {
  int t = blockIdx.x * blockDim.x + threadIdx.x;
  if (t >= B_ * N_) return;
  int b = t / N_;
  int m = assign[t];
  if (m < 0) m = 0;
  if (m >= N_) m = N_ - 1;
  int tc = targ_cat[t];

  const float* row = &pred_cat[(b * N_ + m) * C_];
  float vals[C_];
  const float4* row4 = (const float4*)row;   // 368B row stride = 16B-aligned
#pragma unroll
  for (int k = 0; k < C_ / 4; ++k) {
    float4 w = row4[k];
    vals[4 * k + 0] = w.x; vals[4 * k + 1] = w.y;
    vals[4 * k + 2] = w.z; vals[4 * k + 3] = w.w;
  }
  float mx = -INFINITY;
#pragma unroll
  for (int c = 0; c < C_; ++c) mx = fmaxf(mx, vals[c]);
  float se = 0.0f;
#pragma unroll
  for (int c = 0; c < C_; ++c) se += expf(vals[c] - mx);
  ce[t] = mx + logf(se) - vals[tc];

  float q[4], po[4], to_[4];
  q[0] = pred_bbox[(b * N_ + m) * 4 + 0];
  q[1] = pred_bbox[(b * N_ + m) * 4 + 1];
  q[2] = pred_bbox[(b * N_ + m) * 4 + 2];
  q[3] = pred_bbox[(b * N_ + m) * 4 + 3];
  cxcywh_to_xyxy(q, po);
  q[0] = targ_bbox[t * 4 + 0];
  q[1] = targ_bbox[t * 4 + 1];
  q[2] = targ_bbox[t * 4 + 2];
  q[3] = targ_bbox[t * 4 + 3];
  cxcywh_to_xyxy(q, to_);
  float l = pair_bbox_loss(po, to_);
  bool mk = (tc != 0);
  lb[t] = mk ? l : 0.0f;
  msk[t] = mk ? 1 : 0;
}

// ---- deterministic final reduction -> float32 loss scalar ----

__global__ __launch_bounds__(256) void finalize_k(
    const float* __restrict__ ce, const float* __restrict__ lb,
    const int* __restrict__ msk, float* __restrict__ out) {
  __shared__ double s1[256];
  __shared__ double s2[256];
  __shared__ int s3[256];
  int tid = threadIdx.x;
  double a = 0.0, c2 = 0.0;
  int c3 = 0;
  for (int t = tid; t < B_ * N_; t += 256) {
    a += (double)ce[t]; c2 += (double)lb[t]; c3 += msk[t];
  }
  s1[tid] = a; s2[tid] = c2; s3[tid] = c3;
  __syncthreads();
  for (int off = 128; off > 0; off >>= 1) {
    if (tid < off) {
      s1[tid] += s1[tid + off]; s2[tid] += s2[tid + off]; s3[tid] += s3[tid + off];
    }
    __syncthreads();
  }
  if (tid == 0) {
    double loss = s1[0] / (double)(B_ * N_) + s2[0] / (double)s3[0];
    out[0] = (float)loss;
  }
}

extern "C" void kernel_launch(void* const* d_in, const int* in_sizes, int n_in,
                              void* d_out, int out_size, void* d_ws, size_t ws_size,
                              hipStream_t stream) {
  const int* targ_cat = (const int*)d_in[0];
  const float* targ_bbox = (const float*)d_in[1];
  const float* pred_cat = (const float*)d_in[2];
  const float* pred_bbox = (const float*)d_in[3];
  float* out = (float*)d_out;   // [0] = loss, [1..6400] = assign (as float32)

  char* ws = (char*)d_ws;
  int* assign_ws = (int*)(ws);             // 25.6 KB
  float* ce = (float*)(ws + (32 << 10));   // 25.6 KB
  float* lb = (float*)(ws + (64 << 10));   // 25.6 KB
  int* msk = (int*)(ws + (96 << 10));      // 25.6 KB  (total 128 KB)

  hipLaunchKernelGGL(hungarian_k, dim3(B_), dim3(64), 0, stream,
                     targ_cat, targ_bbox, pred_cat, pred_bbox, assign_ws, out + 1);
  hipLaunchKernelGGL(loss_rows_k, dim3((B_ * N_ + 255) / 256), dim3(256), 0, stream,
                     targ_cat, targ_bbox, pred_cat, pred_bbox, assign_ws, ce, lb, msk);
  hipLaunchKernelGGL(finalize_k, dim3(1), dim3(256), 0, stream, ce, lb, msk, out);
}

// Round 10
// 585.368 us; speedup vs baseline: 1.2211x; 1.1089x over previous
//
#include <hip/hip_runtime.h>
#include <hip/hip_bf16.h>
#include <math.h>

#define B_ 64
#define N_ 100
#define C_ 92

// ---- bbox helpers (f32, fp-contract OFF to mirror strict numpy per-op IEEE) ----

__device__ __forceinline__ void cxcywh_to_xyxy(const float q[4], float o[4]) {
#pragma clang fp contract(off)
  float cx = q[0], cy = q[1], w = q[2], h = q[3];
  o[0] = cx - w * 0.5f;
  o[1] = cy - h * 0.5f;
  o[2] = cx + w * 0.5f;
  o[3] = cy + h * 0.5f;
}

__device__ __forceinline__ float pair_bbox_loss(const float* p, const float* t) {
#pragma clang fp contract(off)
  const float EPS = 1e-7f;
  float px1 = p[0], py1 = p[1], px2 = p[2], py2 = p[3];
  float tx1 = t[0], ty1 = t[1], tx2 = t[2], ty2 = t[3];
  float iw = fminf(px2, tx2) - fmaxf(px1, tx1); iw = fmaxf(iw, 0.0f);
  float ih = fminf(py2, ty2) - fmaxf(py1, ty1); ih = fmaxf(ih, 0.0f);
  float inter = iw * ih;
  float uni = (px2 - px1) * (py2 - py1) + (tx2 - tx1) * (ty2 - ty1) - inter;
  float iou = inter / (uni + EPS);
  float cw = fmaxf(px2, tx2) - fminf(px1, tx1);
  float ch = fmaxf(py2, ty2) - fminf(py1, ty1);
  float diag2 = cw * cw + ch * ch + EPS;
  float dx = (px1 + px2) * 0.5f - (tx1 + tx2) * 0.5f;
  float dy = (py1 + py2) * 0.5f - (ty1 + ty2) * 0.5f;
  float diou = 1.0f - iou + (dx * dx + dy * dy) / diag2;
  float s = 0.0f;
  for (int k = 0; k < 4; ++k) {
    float d = p[k] - t[k];
    float ad = fabsf(d);
    s += (ad < 1.0f) ? 0.5f * d * d : ad - 0.5f;
  }
  return diou + s * 0.25f;
}

__device__ __forceinline__ int rdlane(int v, int srcLane) {
  return __builtin_amdgcn_readlane(v, srcLane);
}

// DPP min step on f64: x = fmin(x, dpp_shuffled(x)); invalid lanes keep old
// (update_dpp old=own value, bound_ctrl=false) -> identity for min. Exact.
template <int CTRL>
__device__ __forceinline__ double dminstep(double x) {
  int lo = __double2loint(x), hi = __double2hiint(x);
  int slo = __builtin_amdgcn_update_dpp(lo, lo, CTRL, 0xF, 0xF, false);
  int shi = __builtin_amdgcn_update_dpp(hi, hi, CTRL, 0xF, 0xF, false);
  return fmin(x, __hiloint2double(shi, slo));
}

// read u[i0] from register-distributed rows
__device__ __forceinline__ double read_u(double uA, double uB, int i0) {
  bool inA = (i0 <= 64);                 // i0 is wave-uniform
  double src = inA ? uA : uB;
  int idx = inA ? (i0 - 1) : (i0 - 65);
  int lo = rdlane(__double2loint(src), idx);
  int hi = rdlane(__double2hiint(src), idx);
  return __hiloint2double(hi, lo);
}

// ---- Hungarian: one wave per batch. ALL SAP state in registers         ----
// ---- (2 cols/lane: v,minv,way,p,used; 2 rows/lane: u + visited flag).  ----
// ---- DPP f64 min-reduce -> delta via lane 63; ballot argmin (np.argmin ----
// ---- first-index tie-break). Cost matrix in LDS (read-only in loop).   ----
// ---- Arithmetic trajectory bit-identical to the numpy e-maxx loop.     ----

__global__ __launch_bounds__(64) void hungarian_k(
    const int* __restrict__ targ_cat, const float* __restrict__ targ_bbox,
    const float* __restrict__ pred_cat, const float* __restrict__ pred_bbox,
    int* __restrict__ assign_ws, float* __restrict__ assign_out) {
  const int b = blockIdx.x;
  const int lane = threadIdx.x;

  __shared__ float costL[N_ * N_];   // [target_row][pred_col]
  __shared__ float tb[N_ * 4];
  __shared__ float pbx[N_ * 4];
  __shared__ int tcat[N_];

  // stage boxes (xyxy) + categories
  for (int i = lane; i < N_; i += 64) {
    float q[4], o[4];
    q[0] = targ_bbox[(b * N_ + i) * 4 + 0];
    q[1] = targ_bbox[(b * N_ + i) * 4 + 1];
    q[2] = targ_bbox[(b * N_ + i) * 4 + 2];
    q[3] = targ_bbox[(b * N_ + i) * 4 + 3];
    cxcywh_to_xyxy(q, o);
    tb[i * 4 + 0] = o[0]; tb[i * 4 + 1] = o[1]; tb[i * 4 + 2] = o[2]; tb[i * 4 + 3] = o[3];
    q[0] = pred_bbox[(b * N_ + i) * 4 + 0];
    q[1] = pred_bbox[(b * N_ + i) * 4 + 1];
    q[2] = pred_bbox[(b * N_ + i) * 4 + 2];
    q[3] = pred_bbox[(b * N_ + i) * 4 + 3];
    cxcywh_to_xyxy(q, o);
    pbx[i * 4 + 0] = o[0]; pbx[i * 4 + 1] = o[1]; pbx[i * 4 + 2] = o[2]; pbx[i * 4 + 3] = o[3];
    tcat[i] = targ_cat[b * N_ + i];
  }
  __syncthreads();

  // cost[n][m] = -pred_cat[b,m,tc(n)] + (tc(n)==0) * pair_bbox_loss(pred m, targ n)
  for (int e = lane; e < N_ * N_; e += 64) {
    int n = e / N_;
    int m = e - n * N_;
    int tc = tcat[n];
    float cc = -pred_cat[(b * N_ + m) * C_ + tc];
    float pl = pair_bbox_loss(&pbx[m * 4], &tb[n * 4]);
    costL[e] = cc + ((tc == 0) ? pl : 0.0f);
  }
  __syncthreads();

  const double INF = __builtin_huge_val();
  const int jA = lane + 1;              // cols 1..64
  const int jB = lane + 65;             // cols 65..100 (lanes 0..35)
  const bool hasB = (jB <= N_);

  double vA = 0.0, vB = 0.0;            // column potentials
  double uA = 0.0, uB = 0.0;            // row potentials: u[lane+1], u[lane+65]
  int pA = 0, pB = 0;                   // matched row per column

  for (int i = 1; i <= N_; ++i) {
    double minvA = INF, minvB = INF;
    int wayA = 0, wayB = 0;
    bool usedA = false, usedB = false;
    bool fA = false, fB = false;        // row-visited flags (u receives deltas)
    int j0 = 0;
    int i0 = i;
    float cA = costL[(i0 - 1) * N_ + (jA - 1)];
    float cB = 0.0f;
    if (hasB) cB = costL[(i0 - 1) * N_ + (jB - 1)];
    double ui0 = read_u(uA, uB, i0);
    int it = 0;
    bool ok = true;

    while (true) {
      // mark used column j0 (first iter: j0==0, none); flag visited row i0
      if (j0 == jA) usedA = true;
      if (j0 == jB) usedB = true;
      fA = fA || (i0 == jA);
      fB = fB || (i0 == jB);

      if (!usedA) {
        double cur = (double)cA - ui0 - vA;
        if (cur < minvA) { minvA = cur; wayA = j0; }
      }
      if (hasB && !usedB) {
        double cur = (double)cB - ui0 - vB;
        if (cur < minvB) { minvB = cur; wayB = j0; }
      }

      // exact f64 min over unused columns: DPP reduce -> lane 63 -> SGPR
      double cvA = usedA ? INF : minvA;
      double cvB = (hasB && !usedB) ? minvB : INF;
      double rm = fmin(cvA, cvB);
      rm = dminstep<0x111>(rm);         // row_shr:1
      rm = dminstep<0x112>(rm);         // row_shr:2
      rm = dminstep<0x114>(rm);         // row_shr:4
      rm = dminstep<0x118>(rm);         // row_shr:8
      rm = dminstep<0x142>(rm);         // row_bcast15
      rm = dminstep<0x143>(rm);         // row_bcast31 -> lane 63 = global min
      double delta = __hiloint2double(rdlane(__double2hiint(rm), 63),
                                      rdlane(__double2loint(rm), 63));
      if (delta == INF) { ok = false; break; }   // unreachable for valid input

      // first-index argmin (branchless): A-range cols win over B-range
      unsigned long long mA = __ballot(cvA == delta);
      unsigned long long mB = __ballot(cvB == delta);
      int j1 = mA ? (__builtin_ctzll(mA) + 1)
                  : (mB ? (__builtin_ctzll(mB) + 65) : 0);
      if (j1 == 0) { ok = false; break; }

      // next row + software-pipelined loads (issue before the update block)
      int pj1 = (j1 <= 64) ? rdlane(pA, j1 - 1) : rdlane(pB, j1 - 65);
      int ni0 = (pj1 == 0) ? 1 : pj1;   // dummy row if phase ends
      float nA = costL[(ni0 - 1) * N_ + (jA - 1)];
      float nB = 0.0f;
      if (hasB) nB = costL[(ni0 - 1) * N_ + (jB - 1)];
      double nui0 = read_u(uA, uB, ni0);  // row ni0 untouched this iteration (proven)

      // updates: visited rows u += delta; used cols v -= delta; else minv -= delta
      if (fA) uA += delta;
      if (fB) uB += delta;
      if (usedA) { vA -= delta; } else { minvA -= delta; }
      if (hasB) {
        if (usedB) { vB -= delta; } else { minvB -= delta; }
      }

      j0 = j1;
      if (pj1 == 0) break;              // reached an unmatched column
      i0 = ni0; ui0 = nui0; cA = nA; cB = nB;
      if (++it > 2 * N_ + 8) { ok = false; break; }
    }

    // augmenting-path reconstruction: uniform scalar walk over register state
    if (ok) {
      int jj = j0;
      int hop = 0;
      while (jj != 0 && ++hop <= N_ + 2) {
        int jp = (jj <= 64) ? rdlane(wayA, jj - 1) : rdlane(wayB, jj - 65);
        int pv = (jp == 0) ? i
                           : ((jp <= 64) ? rdlane(pA, jp - 1) : rdlane(pB, jp - 65));
        if (jj <= 64) { if (lane == jj - 1) pA = pv; }
        else          { if (lane == jj - 65) pB = pv; }
        jj = jp;
      }
    }
  }

  // ans[p[j]-1] = j-1  (float32 outputs)
  {
    int row = pA - 1;
    if (row < 0) row = 0;
    if (row >= N_) row = N_ - 1;
    assign_ws[b * N_ + row] = jA - 1;
    assign_out[b * N_ + row] = (float)(jA - 1);
    if (hasB) {
      int r2 = pB - 1;
      if (r2 < 0) r2 = 0;
      if (r2 >= N_) r2 = N_ - 1;
      assign_ws[b * N_ + r2] = jB - 1;
      assign_out[b * N_ + r2] = (float)(jB - 1);
    }
  }
}

// ---- per-row losses: CE (log_softmax gather) + matched bbox pair loss ----

__global__ __launch_bounds__(256) void loss_rows_k(
    const int* __restrict__ targ_cat, const float* __restrict__ targ_bbox,
    const float* __restrict__ pred_cat, const float* __restrict__ pred_bbox,
    const int* __restrict__ assign,
    float* __restrict__ ce, float* __restrict__ lb, int* __restrict__ msk) {
  int t = blockIdx.x * blockDim.x + threadIdx.x;
  if (t >= B_ * N_) return;
  int b = t / N_;
  int m = assign[t];
  if (m < 0) m = 0;
  if (m >= N_) m = N_ - 1;
  int tc = targ_cat[t];

  const float* row = &pred_cat[(b * N_ + m) * C_];
  float vals[C_];
  const float4* row4 = (const float4*)row;   // 368B row stride = 16B-aligned
#pragma unroll
  for (int k = 0; k < C_ / 4; ++k) {
    float4 w = row4[k];
    vals[4 * k + 0] = w.x; vals[4 * k + 1] = w.y;
    vals[4 * k + 2] = w.z; vals[4 * k + 3] = w.w;
  }
  float mx = -INFINITY;
#pragma unroll
  for (int c = 0; c < C_; ++c) mx = fmaxf(mx, vals[c]);
  float se = 0.0f;
#pragma unroll
  for (int c = 0; c < C_; ++c) se += expf(vals[c] - mx);
  ce[t] = mx + logf(se) - vals[tc];

  float q[4], po[4], to_[4];
  q[0] = pred_bbox[(b * N_ + m) * 4 + 0];
  q[1] = pred_bbox[(b * N_ + m) * 4 + 1];
  q[2] = pred_bbox[(b * N_ + m) * 4 + 2];
  q[3] = pred_bbox[(b * N_ + m) * 4 + 3];
  cxcywh_to_xyxy(q, po);
  q[0] = targ_bbox[t * 4 + 0];
  q[1] = targ_bbox[t * 4 + 1];
  q[2] = targ_bbox[t * 4 + 2];
  q[3] = targ_bbox[t * 4 + 3];
  cxcywh_to_xyxy(q, to_);
  float l = pair_bbox_loss(po, to_);
  bool mk = (tc != 0);
  lb[t] = mk ? l : 0.0f;
  msk[t] = mk ? 1 : 0;
}

// ---- deterministic final reduction -> float32 loss scalar ----

__global__ __launch_bounds__(256) void finalize_k(
    const float* __restrict__ ce, const float* __restrict__ lb,
    const int* __restrict__ msk, float* __restrict__ out) {
  __shared__ double s1[256];
  __shared__ double s2[256];
  __shared__ int s3[256];
  int tid = threadIdx.x;
  double a = 0.0, c2 = 0.0;
  int c3 = 0;
  for (int t = tid; t < B_ * N_; t += 256) {
    a += (double)ce[t]; c2 += (double)lb[t]; c3 += msk[t];
  }
  s1[tid] = a; s2[tid] = c2; s3[tid] = c3;
  __syncthreads();
  for (int off = 128; off > 0; off >>= 1) {
    if (tid < off) {
      s1[tid] += s1[tid + off]; s2[tid] += s2[tid + off]; s3[tid] += s3[tid + off];
    }
    __syncthreads();
  }
  if (tid == 0) {
    double loss = s1[0] / (double)(B_ * N_) + s2[0] / (double)s3[0];
    out[0] = (float)loss;
  }
}

extern "C" void kernel_launch(void* const* d_in, const int* in_sizes, int n_in,
                              void* d_out, int out_size, void* d_ws, size_t ws_size,
                              hipStream_t stream) {
  const int* targ_cat = (const int*)d_in[0];
  const float* targ_bbox = (const float*)d_in[1];
  const float* pred_cat = (const float*)d_in[2];
  const float* pred_bbox = (const float*)d_in[3];
  float* out = (float*)d_out;   // [0] = loss, [1..6400] = assign (as float32)

  char* ws = (char*)d_ws;
  int* assign_ws = (int*)(ws);             // 25.6 KB
  float* ce = (float*)(ws + (32 << 10));   // 25.6 KB
  float* lb = (float*)(ws + (64 << 10));   // 25.6 KB
  int* msk = (int*)(ws + (96 << 10));      // 25.6 KB  (total 128 KB)

  hipLaunchKernelGGL(hungarian_k, dim3(B_), dim3(64), 0, stream,
                     targ_cat, targ_bbox, pred_cat, pred_bbox, assign_ws, out + 1);
  hipLaunchKernelGGL(loss_rows_k, dim3((B_ * N_ + 255) / 256), dim3(256), 0, stream,
                     targ_cat, targ_bbox, pred_cat, pred_bbox, assign_ws, ce, lb, msk);
  hipLaunchKernelGGL(finalize_k, dim3(1), dim3(256), 0, stream, ce, lb, msk, out);
}